// Round 1
// 269.988 us; speedup vs baseline: 1.0614x; 1.0614x over previous
//
#include <hip/hip_runtime.h>
#include <utility>

// Problem constants: N=262144 rows, NX=NQ=64, NU=16, fp32.
#define NROWS 262144
#define BT 512                 // threads/block
#define RPB 128                // rows/block (= BT/4)

typedef float f16v __attribute__((ext_vector_type(16)));

// d_ws layout (floats) — two contiguous 9280-float phase blocks:
//  phase1 @0    : C1T[4096] | D11T[4096] | D12T[1024] | bv[64]
//  phase2 @9280 : AT [4096] | B1T [4096] | B2T [1024] | bx[64]
// In-block offsets (same for LDS): M0@0, M1@4096, M2@8192, bias@9216.
//  C1T[j*64+i]=C1[i][j]  D11T[i*64+k]=D11[k][i] (zeros at k<=i come from input)
//  D12T[j*64+i]=D12[i][j]  AT[j*64+k]=A[k][j]  B1T[i*64+k]=B1[k][i]
//  B2T[j*64+k]=B2[k][j]

__global__ void prep_kernel(const float* __restrict__ A, const float* __restrict__ B1,
                            const float* __restrict__ B2, const float* __restrict__ C1,
                            const float* __restrict__ D11, const float* __restrict__ D12,
                            const float* __restrict__ bv, const float* __restrict__ bx,
                            float* __restrict__ ws) {
    int g = blockIdx.x * 256 + threadIdx.x;
    if (g < 4096) {
        int r = g >> 6, c = g & 63;       // source row r, col c (64x64 row-major)
        int to = c * 64 + r;
        ws[0     + to] = C1[g];           // C1T
        ws[4096  + to] = D11[g];          // D11T
        ws[9280  + to] = A[g];            // AT
        ws[13376 + to] = B1[g];           // B1T
    }
    if (g < 1024) {
        int r = g >> 4, c = g & 15;       // 64x16 row-major source
        int to = c * 64 + r;
        ws[8192  + to] = D12[g];          // D12T
        ws[17472 + to] = B2[g];           // B2T
    }
    if (g < 64) {
        ws[9216  + g] = bv[g];
        ws[18496 + g] = bx[g];
    }
}

__device__ __forceinline__ f16v lds16(const float* p) { return *(const f16v*)p; }

// Quad-lane broadcast via DPP quad_perm:[Q,Q,Q,Q] — pure VALU (~2 cyc).
// Replaces ds_swizzle, whose result waits in the in-order lgkmcnt queue
// behind the column ds_reads (64-step serial chain at LDS latency).
template<int Q>
__device__ __forceinline__ float qbcast(float v) {
    return __int_as_float(__builtin_amdgcn_update_dpp(
        0, __float_as_int(v), Q * 0x55, 0xF, 0xF, true));
}

// Substitution step I: broadcast w_I's pre-activation from its owner lane
// (quad lane I>>4), relu on every lane, then uniform FMA — zeros in D11T
// column I make non-future entries exact no-ops.
template<int I>
__device__ __forceinline__ void substep(f16v& s, const float* D11s, int c16, int c) {
    const float wv = fmaxf(qbcast<(I >> 4)>(s[I & 15]), 0.0f);
    s += lds16(D11s + I * 64 + c16) * wv;          // D11T[I][I]==0, safe for owner
    s[I & 15] = (c == (I >> 4)) ? wv : s[I & 15];  // owner finalizes its element
}

template<int... Is>
__device__ __forceinline__ void subst_all(f16v& s, const float* D11s, int c16, int c,
                                          std::integer_sequence<int, Is...>) {
    (substep<Is>(s, D11s, c16, c), ...);
}

// Phase-2 B1·w: w lives entirely in the quad's registers (4 lanes x 16 elems),
// so broadcast w_J from the owner lane — no global w round-trip at all.
template<int J>
__device__ __forceinline__ void b1step(f16v& acc, const f16v& w, const float* B1s, int c16) {
    acc += lds16(B1s + J * 64 + c16) * qbcast<(J >> 4)>(w[J & 15]);
}

template<int... Js>
__device__ __forceinline__ void b1_all(f16v& acc, const f16v& w, const float* B1s, int c16,
                                       std::integer_sequence<int, Js...>) {
    (b1step<Js>(acc, w, B1s, c16), ...);
}

// Fused kernel: quad (4 lanes) per row; each lane owns a 16-output chunk.
// Phase1: s = bv + C1 x + D12 u; substitution -> w (kept in registers).
// Phase2: out = bx + B1 w + A x + B2 u (B1·w first so s dies early).
__global__ __launch_bounds__(BT, 4) void renl2_fused(const float* __restrict__ x,
                                                     const float* __restrict__ u,
                                                     const float* __restrict__ ws,
                                                     float* __restrict__ out) {
    __shared__ float sm[9280];            // 37.1 KB -> 4 blocks/CU
    const int tid = threadIdx.x;
    const int c   = tid & 3;              // quad chunk id
    const int c16 = c << 4;
    const int r   = tid >> 2;             // row within block
    const int row = blockIdx.x * RPB + r;

    const float* __restrict__ xr = x + (size_t)row * 64;
    const float* __restrict__ ur = u + (size_t)row * 16;

    // ---- stage phase-1 matrices ----
#pragma unroll 4
    for (int i = tid; i < 9280; i += BT) sm[i] = ws[i];
    __syncthreads();

    // ---- phase 1: s = bv + C1 x + D12 u ----
    f16v s = lds16(sm + 9216 + c16);
#pragma unroll 1
    for (int j = 0; j < 64; j += 4) {
        const float4 xv = *(const float4*)(xr + j);
#pragma unroll
        for (int jj = 0; jj < 4; jj++) {
            const float xs = (jj == 0) ? xv.x : (jj == 1) ? xv.y : (jj == 2) ? xv.z : xv.w;
            s += lds16(sm + (j + jj) * 64 + c16) * xs;           // C1T @0
        }
    }
    {
        const float4 uv0 = *(const float4*)(ur);
        const float4 uv1 = *(const float4*)(ur + 4);
        const float4 uv2 = *(const float4*)(ur + 8);
        const float4 uv3 = *(const float4*)(ur + 12);
        const float us[16] = {uv0.x,uv0.y,uv0.z,uv0.w, uv1.x,uv1.y,uv1.z,uv1.w,
                              uv2.x,uv2.y,uv2.z,uv2.w, uv3.x,uv3.y,uv3.z,uv3.w};
#pragma unroll
        for (int j = 0; j < 16; j++)
            s += lds16(sm + 8192 + j * 64 + c16) * us[j];         // D12T @8192
    }

    // ---- substitution (intra-quad DPP broadcast, branchless, VALU-only) ----
    subst_all(s, sm + 4096, c16, c, std::make_integer_sequence<int, 64>{});

    // ---- overlay phase-2 matrices ----
    __syncthreads();
#pragma unroll 4
    for (int i = tid; i < 9280; i += BT) sm[i] = ws[9280 + i];
    __syncthreads();

    // ---- phase 2: acc = bx + B1 w  (w broadcast from quad registers) ----
    f16v acc = lds16(sm + 9216 + c16);
    b1_all(acc, s, sm + 4096, c16, std::make_integer_sequence<int, 64>{}); // B1T @4096

    // ---- + A x ----
#pragma unroll 1
    for (int j = 0; j < 64; j += 4) {
        const float4 xv = *(const float4*)(xr + j);
#pragma unroll
        for (int jj = 0; jj < 4; jj++) {
            const float xs = (jj == 0) ? xv.x : (jj == 1) ? xv.y : (jj == 2) ? xv.z : xv.w;
            acc += lds16(sm + (j + jj) * 64 + c16) * xs;          // AT @0
        }
    }

    // ---- + B2 u ----
    {
        const float4 uv0 = *(const float4*)(ur);
        const float4 uv1 = *(const float4*)(ur + 4);
        const float4 uv2 = *(const float4*)(ur + 8);
        const float4 uv3 = *(const float4*)(ur + 12);
        const float us[16] = {uv0.x,uv0.y,uv0.z,uv0.w, uv1.x,uv1.y,uv1.z,uv1.w,
                              uv2.x,uv2.y,uv2.z,uv2.w, uv3.x,uv3.y,uv3.z,uv3.w};
#pragma unroll
        for (int j = 0; j < 16; j++)
            acc += lds16(sm + 8192 + j * 64 + c16) * us[j];       // B2T @8192
    }

    // ---- single store: x_dot ----
    float* outr = out + (size_t)row * 64;
    *(float4*)(outr + c16)      = float4{acc[0],  acc[1],  acc[2],  acc[3]};
    *(float4*)(outr + c16 + 4)  = float4{acc[4],  acc[5],  acc[6],  acc[7]};
    *(float4*)(outr + c16 + 8)  = float4{acc[8],  acc[9],  acc[10], acc[11]};
    *(float4*)(outr + c16 + 12) = float4{acc[12], acc[13], acc[14], acc[15]};
}

extern "C" void kernel_launch(void* const* d_in, const int* in_sizes, int n_in,
                              void* d_out, int out_size, void* d_ws, size_t ws_size,
                              hipStream_t stream) {
    const float* x   = (const float*)d_in[0];
    const float* u   = (const float*)d_in[1];
    const float* A   = (const float*)d_in[2];
    const float* B1  = (const float*)d_in[3];
    const float* B2  = (const float*)d_in[4];
    const float* C1  = (const float*)d_in[5];
    const float* D11 = (const float*)d_in[6];
    const float* D12 = (const float*)d_in[7];
    const float* bv  = (const float*)d_in[8];
    const float* bx  = (const float*)d_in[9];
    float* out = (float*)d_out;
    float* ws  = (float*)d_ws;

    prep_kernel<<<16, 256, 0, stream>>>(A, B1, B2, C1, D11, D12, bv, bx, ws);
    renl2_fused<<<NROWS / RPB, BT, 0, stream>>>(x, u, ws, out);
}